// Round 7
// baseline (170.777 us; speedup 1.0000x reference)
//
#include <hip/hip_runtime.h>

// DistributionLoss: local 7x7xC std (zero-padded) of two [16,3,512,512] fp32
// tensors, smooth-L1 mean between std maps -> scalar.
//
// R15: single-wave workgroups, column-per-lane scalar streaming.
// R14 post-mortem: (a) __syncthreads drains vmcnt -> any DMA prefetch dies
// at every barrier; (b) >~64 VGPR of live state gets spilled (R9/R11/R12/
// R14 all hit this). Fix both structurally:
//  - 1 wave per block -> ZERO barriers. Wave-internal LDS ordering via
//    explicit s_waitcnt lgkmcnt(0) fences (wave-synchronous idiom; fences
//    also stop the compiler reordering provably-disjoint per-lane LDS ops
//    that alias ACROSS lanes).
//  - 1 output column per lane -> vertical 7-tap ring = 4 scalars x 8 slots
//    = 32 VGPR (the float4 rings that spilled were 128).
//  - Per row-iter: 12 scalar loads (6 main + 6 broadcast-line halo),
//    channel reduce, t/u -> 1.4KB LDS row (stride 5 dwords: 5 coprime 32,
//    conflict-free), fence, 7-tap horizontal sum, ring slide, std + SL1.
//  - Latency hiding by TLP: grid 8x32x16 = 4096 one-wave blocks = 16
//    waves/CU, ~1.7KB in flight each (+1-row software prefetch).
//  - Strip = 64 cols x SH=16 rows; NR=22 input rows; refetch 1.375x
//    (halo rows mostly L2-absorbed across adjacent concurrent strips).

#define SH    16
#define NR    (SH + 6)         // 22 input rows per strip
#define NT    64
#define STR   5                // LDS dword stride per column position

__global__ __launch_bounds__(NT, 4) void dist_loss_kernel(
    const float* __restrict__ pred,
    const float* __restrict__ tgt,
    float* __restrict__ out)
{
    constexpr int   W = 512, H = 512;
    constexpr float INV_N     = 1.0f / 147.0f;
    constexpr float INV_TOTAL = 1.0f / (16.0f * 512.0f * 512.0f);

    __shared__ float sh[72 * STR];   // 72 col-positions x {t0,u0,t1,u1}, 1.44 KB

    const int l  = threadIdx.x;      // 0..63
    const int x0 = blockIdx.x * 64;  // col group
    const int ys = blockIdx.y * SH;  // strip top
    const int b  = blockIdx.z;

    const size_t plane = (size_t)H * W;
    const float* bp = pred + (size_t)b * 3 * plane;
    const float* bt = tgt  + (size_t)b * 3 * plane;

    // lane-constant geometry. Position e <-> image col x0+e-4.
    // main: e = l (cols x0-4 .. x0+59); halo: e = 64+l, lanes 0..7
    // (cols x0+60 .. x0+67). Clamped addresses; garbage zeroed by masks.
    const int   colM   = x0 + l - 4;
    const int   cMain  = max(colM, 0);                 // right side always < W
    const int   colH   = x0 + 60 + min(l, 7);          // lanes >=8 broadcast lane7's line
    const int   cHalo  = min(colH, W - 1);
    const float mMainC = (colM >= 0) ? 1.f : 0.f;
    const float mHaloC = (colH < W) ? 1.f : 0.f;
    const bool  haloLn = (l < 8);

    // vertical 7-tap register ring: 4 scalar kinds x 8 slots = 32 VGPR
    float rh0[8], rg0[8], rh1[8], rg1[8];
    #pragma unroll
    for (int r = 0; r < 8; ++r) { rh0[r] = rg0[r] = rh1[r] = rg1[r] = 0.f; }
    float S0 = 0.f, Q0 = 0.f, S1 = 0.f, Q1 = 0.f, acc = 0.f;

    // double-buffered scalar load set (12 values/row)
    float A0[2], A1[2], A2[2], B0[2], B1[2], B2[2];          // main
    float h0v[2], h1v[2], h2v[2], h3v[2], h4v[2], h5v[2];    // halo

    #define LOADROW(P, r_) do {                                              \
        const int gyc_ = min(max(ys - 3 + (r_), 0), H - 1);                  \
        const float* rp_ = bp + (size_t)gyc_ * W;                            \
        const float* rt_ = bt + (size_t)gyc_ * W;                            \
        A0[P] = rp_[cMain];  A1[P] = rp_[plane + cMain];                     \
        A2[P] = rp_[2 * plane + cMain];                                      \
        B0[P] = rt_[cMain];  B1[P] = rt_[plane + cMain];                     \
        B2[P] = rt_[2 * plane + cMain];                                      \
        h0v[P] = rp_[cHalo]; h1v[P] = rp_[plane + cHalo];                    \
        h2v[P] = rp_[2 * plane + cHalo];                                     \
        h3v[P] = rt_[cHalo]; h4v[P] = rt_[plane + cHalo];                    \
        h5v[P] = rt_[2 * plane + cHalo];                                     \
    } while (0)

    #define FENCE() asm volatile("s_waitcnt lgkmcnt(0)" ::: "memory")

    #define CONSUME(i_, P, JN, JO) do {                                      \
        const int   gy_ = ys - 3 + (i_);                                     \
        const float rm_ = ((unsigned)gy_ < (unsigned)H) ? 1.f : 0.f;         \
        const float mM_ = mMainC * rm_;                                      \
        const float mH_ = mHaloC * rm_;                                      \
        float t0 = (A0[P] + A1[P] + A2[P]) * mM_;                            \
        float u0 = fmaf(A0[P], A0[P],                                        \
                   fmaf(A1[P], A1[P], A2[P] * A2[P])) * mM_;                 \
        float t1 = (B0[P] + B1[P] + B2[P]) * mM_;                            \
        float u1 = fmaf(B0[P], B0[P],                                        \
                   fmaf(B1[P], B1[P], B2[P] * B2[P])) * mM_;                 \
        float th0 = (h0v[P] + h1v[P] + h2v[P]) * mH_;                        \
        float uh0 = fmaf(h0v[P], h0v[P],                                     \
                    fmaf(h1v[P], h1v[P], h2v[P] * h2v[P])) * mH_;            \
        float th1 = (h3v[P] + h4v[P] + h5v[P]) * mH_;                        \
        float uh1 = fmaf(h3v[P], h3v[P],                                     \
                    fmaf(h4v[P], h4v[P], h5v[P] * h5v[P])) * mH_;            \
        FENCE();   /* WAR: prior iter's reads retire before overwrite */     \
        sh[l * STR + 0] = t0;  sh[l * STR + 1] = u0;                         \
        sh[l * STR + 2] = t1;  sh[l * STR + 3] = u1;                         \
        if (haloLn) {                                                        \
            sh[(64 + l) * STR + 0] = th0; sh[(64 + l) * STR + 1] = uh0;      \
            sh[(64 + l) * STR + 2] = th1; sh[(64 + l) * STR + 3] = uh1;      \
        }                                                                    \
        FENCE();   /* RAW: writes visible wave-wide before cross-lane reads */\
        float hh0 = 0.f, gg0 = 0.f, hh1 = 0.f, gg1 = 0.f;                    \
        _Pragma("unroll")                                                    \
        for (int j2 = 1; j2 <= 7; ++j2) {                                    \
            const float* q_ = &sh[(l + j2) * STR];                           \
            hh0 += q_[0]; gg0 += q_[1]; hh1 += q_[2]; gg1 += q_[3];          \
        }                                                                    \
        S0 += hh0 - rh0[JO]; rh0[JN] = hh0;                                  \
        Q0 += gg0 - rg0[JO]; rg0[JN] = gg0;                                  \
        S1 += hh1 - rh1[JO]; rh1[JN] = hh1;                                  \
        Q1 += gg1 - rg1[JO]; rg1[JN] = gg1;                                  \
        if ((i_) >= 6) {                                                     \
            float mu0 = S0 * INV_N;                                          \
            float sd0 = sqrtf(fmaf(-mu0, mu0, Q0 * INV_N) + 1e-8f);          \
            float mu1 = S1 * INV_N;                                          \
            float sd1 = sqrtf(fmaf(-mu1, mu1, Q1 * INV_N) + 1e-8f);          \
            float d_  = sd0 - sd1;                                           \
            float ad_ = fabsf(d_);                                           \
            acc += (ad_ < 1.f) ? 0.5f * d_ * d_ : (ad_ - 0.5f);              \
        }                                                                    \
    } while (0)

    LOADROW(0, 0);

    // 22 iterations; unroll period 8 keeps ring slots / buffer parity static
    #pragma unroll 1
    for (int g = 0; g < 3; ++g) {
        #pragma unroll
        for (int j = 0; j < 8; ++j) {
            const int i = g * 8 + j;
            if (i < NR) {
                LOADROW((j + 1) & 1, i + 1);   // prefetch next row (clamped-safe)
                CONSUME(i, j & 1, j, (j + 1) & 7);
            }
        }
    }

    #undef CONSUME
    #undef FENCE
    #undef LOADROW

    // wave reduction + one atomic per block
    #pragma unroll
    for (int off = 32; off > 0; off >>= 1)
        acc += __shfl_down(acc, off, 64);
    if (l == 0) atomicAdd(out, acc * INV_TOTAL);
}

extern "C" void kernel_launch(void* const* d_in, const int* in_sizes, int n_in,
                              void* d_out, int out_size, void* d_ws, size_t ws_size,
                              hipStream_t stream) {
    const float* pred = (const float*)d_in[0];
    const float* tgt  = (const float*)d_in[1];
    float* out = (float*)d_out;

    hipMemsetAsync(out, 0, sizeof(float), stream);

    dim3 grid(512 / 64, 512 / SH, 16);   // 8 x 32 x 16 = 4096 one-wave blocks
    dist_loss_kernel<<<grid, NT, 0, stream>>>(pred, tgt, out);
}

// Round 8
// 129.388 us; speedup vs baseline: 1.3199x; 1.3199x over previous
//
#include <hip/hip_runtime.h>

// DistributionLoss: local 7x7xC std (zero-padded) of two [16,3,512,512] fp32
// tensors, smooth-L1 mean between std maps -> scalar.
//
// R16: R11 (the 40.7us best: pinned-asm load pipeline + two-phase LDS) with
// its two measured defects fixed, nothing else:
//  1. launch_bounds(256,2)->(256,4): VGPR cap 128 and 4 blocks/CU (16
//     waves/CU; LDS 4x38.5KB=154KB<160KB). R11 ran 2 blocks/CU (occ 26%).
//  2. Lean pointers: R11 reported VGPR=64 vs ~120 peak-live -> allocator
//     spilled half the asm-output quads to scratch (L2-absorbed, but the
//     spill chains re-serialized the pipeline). Now per slot: 3 base ptrs
//     + byte-offsets cA (leftOK?-16:0) / cE (rightOK?32:16); A/E addresses
//     formed at issue, D via offset:16 imm. Peak live ~120 < 128 cap.
// Pipeline (R11 verbatim): 3 task slots, 12 pinned global_load_dwordx4
// each, 24 quads outstanding at each WAITV(12); drain 12/0. Halo loads use
// clamped addresses + 0/1 mask multiply (always legal, wave-uniform vmcnt).
// Phase B (vertical 7-tap + std + fused smooth-L1) and reduction unchanged.

typedef float f32x4 __attribute__((ext_vector_type(4)));

#define K     7
#define PAD   3
#define TSX   64
#define TSY   32
#define HR    (TSY + K - 1)   // 38 halo rows
#define LDSW  64              // LDS row stride (floats)
#define NT    256
#define NTASK (2 * HR * 8)    // 608 fused tasks (both inputs)

#define LOADQ(dst, ptr, OFF)                                        \
    asm volatile("global_load_dwordx4 %0, %1, off offset:" OFF      \
                 : "=v"(dst) : "v"(ptr))

#define WAITV(N) do {                                               \
    asm volatile("s_waitcnt vmcnt(" #N ")" ::: "memory");           \
    __builtin_amdgcn_sched_barrier(0);                              \
} while (0)

__global__ __launch_bounds__(NT, 4) void dist_loss_kernel(
    const float* __restrict__ pred,
    const float* __restrict__ tgt,
    float* __restrict__ out)
{
    constexpr int   C = 3, H = 512, W = 512;
    constexpr float INV_N     = 1.0f / (C * K * K);              // 1/147
    constexpr float INV_TOTAL = 1.0f / (16.0f * 512.0f * 512.0f);

    __shared__ float sh_s[2][HR][LDSW];   // horizontal 7-tap of channel sum
    __shared__ float sh_q[2][HR][LDSW];   // horizontal 7-tap of channel sum-sq

    const int    tid  = threadIdx.x;
    const int    tx0  = blockIdx.x * TSX;
    const int    ty0  = blockIdx.y * TSY;
    const int    b    = blockIdx.z;
    const size_t plane = (size_t)H * W;
    const size_t planeB = plane * sizeof(float);

    const float* base0 = pred + (size_t)b * C * plane;
    const float* base1 = tgt  + (size_t)b * C * plane;

    float* shs = &sh_s[0][0][0];
    float* shq = &sh_q[0][0][0];

    // ---- Phase A: 3-slot pinned pipeline (peak 2 slots live) ----
    #define DECL_SLOT(S)                                                     \
        const char *rB0_##S, *rB1_##S, *rB2_##S;                             \
        int cA_##S, cE_##S, idx_##S;                                         \
        float m_##S, mL_##S, mR_##S;                                         \
        f32x4 qA0_##S, qB0_##S, qD0_##S, qE0_##S,                            \
              qA1_##S, qB1_##S, qD1_##S, qE1_##S,                            \
              qA2_##S, qB2_##S, qD2_##S, qE2_##S;

    // decode task t; clamped (always-legal) addresses; garbage masked later
    #define SETUP(S, t) do {                                                 \
        const int which = ((t) >= HR * 8) ? 1 : 0;                           \
        const int tt    = (t) - which * (HR * 8);                            \
        const int row   = tt >> 3, cg = tt & 7;                              \
        const int gy    = ty0 - PAD + row;                                   \
        m_##S  = ((unsigned)gy < (unsigned)H) ? 1.f : 0.f;                   \
        const int gyc = min(max(gy, 0), H - 1);                              \
        const int gx0 = tx0 + (cg << 3);                                     \
        mL_##S = (gx0 > 0)   ? 1.f : 0.f;                                    \
        mR_##S = (gx0 < 504) ? 1.f : 0.f;                                    \
        const float* base = which ? base1 : base0;                           \
        rB0_##S = (const char*)(base + (size_t)gyc * W + gx0);               \
        rB1_##S = rB0_##S + planeB;                                          \
        rB2_##S = rB1_##S + planeB;                                          \
        cA_##S  = (gx0 > 0)   ? -16 : 0;                                     \
        cE_##S  = (gx0 < 504) ?  32 : 16;                                    \
        idx_##S = (which * HR + row) * LDSW + (cg << 3);                     \
    } while (0)

    #define ISSUE(S) do {                                                    \
        LOADQ(qA0_##S, rB0_##S + cA_##S, "0");                               \
        LOADQ(qB0_##S, rB0_##S,          "0");                               \
        LOADQ(qD0_##S, rB0_##S,          "16");                              \
        LOADQ(qE0_##S, rB0_##S + cE_##S, "0");                               \
        LOADQ(qA1_##S, rB1_##S + cA_##S, "0");                               \
        LOADQ(qB1_##S, rB1_##S,          "0");                               \
        LOADQ(qD1_##S, rB1_##S,          "16");                              \
        LOADQ(qE1_##S, rB1_##S + cE_##S, "0");                               \
        LOADQ(qA2_##S, rB2_##S + cA_##S, "0");                               \
        LOADQ(qB2_##S, rB2_##S,          "0");                               \
        LOADQ(qD2_##S, rB2_##S,          "16");                              \
        LOADQ(qE2_##S, rB2_##S + cE_##S, "0");                               \
    } while (0)

    #define CONSUME(S) do {                                                  \
        f32x4 tl = qA0_##S + qA1_##S + qA2_##S;                              \
        f32x4 ta = qB0_##S + qB1_##S + qB2_##S;                              \
        f32x4 tb = qD0_##S + qD1_##S + qD2_##S;                              \
        f32x4 tr = qE0_##S + qE1_##S + qE2_##S;                              \
        f32x4 ul = qA0_##S*qA0_##S + qA1_##S*qA1_##S + qA2_##S*qA2_##S;      \
        f32x4 ua = qB0_##S*qB0_##S + qB1_##S*qB1_##S + qB2_##S*qB2_##S;      \
        f32x4 ub = qD0_##S*qD0_##S + qD1_##S*qD1_##S + qD2_##S*qD2_##S;      \
        f32x4 ur = qE0_##S*qE0_##S + qE1_##S*qE1_##S + qE2_##S*qE2_##S;      \
        tl[1] *= mL_##S; tl[2] *= mL_##S; tl[3] *= mL_##S;                   \
        ul[1] *= mL_##S; ul[2] *= mL_##S; ul[3] *= mL_##S;                   \
        tr[0] *= mR_##S; tr[1] *= mR_##S; tr[2] *= mR_##S;                   \
        ur[0] *= mR_##S; ur[1] *= mR_##S; ur[2] *= mR_##S;                   \
        float h0 = tl[1]+tl[2]+tl[3]+ta[0]+ta[1]+ta[2]+ta[3];                \
        float h1 = h0 - tl[1] + tb[0];                                       \
        float h2 = h1 - tl[2] + tb[1];                                       \
        float h3 = h2 - tl[3] + tb[2];                                       \
        float h4 = h3 - ta[0] + tb[3];                                       \
        float h5 = h4 - ta[1] + tr[0];                                       \
        float h6 = h5 - ta[2] + tr[1];                                       \
        float h7 = h6 - ta[3] + tr[2];                                       \
        float g0 = ul[1]+ul[2]+ul[3]+ua[0]+ua[1]+ua[2]+ua[3];                \
        float g1 = g0 - ul[1] + ub[0];                                       \
        float g2 = g1 - ul[2] + ub[1];                                       \
        float g3 = g2 - ul[3] + ub[2];                                       \
        float g4 = g3 - ua[0] + ub[3];                                       \
        float g5 = g4 - ua[1] + ur[0];                                       \
        float g6 = g5 - ua[2] + ur[1];                                       \
        float g7 = g6 - ua[3] + ur[2];                                       \
        const float mm = m_##S;                                              \
        *(f32x4*)&shs[idx_##S]     = (f32x4){h0*mm, h1*mm, h2*mm, h3*mm};    \
        *(f32x4*)&shs[idx_##S + 4] = (f32x4){h4*mm, h5*mm, h6*mm, h7*mm};    \
        *(f32x4*)&shq[idx_##S]     = (f32x4){g0*mm, g1*mm, g2*mm, g3*mm};    \
        *(f32x4*)&shq[idx_##S + 4] = (f32x4){g4*mm, g5*mm, g6*mm, g7*mm};    \
    } while (0)

    DECL_SLOT(0);
    DECL_SLOT(1);
    const int t0 = tid;
    const int t1 = tid + NT;
    const int t2 = min(tid + 2 * NT, NTASK - 1);  // dup tail: benign same-value writes

    SETUP(0, t0); ISSUE(0);
    SETUP(1, t1); ISSUE(1);
    WAITV(12);            // T0's 12 loads done; T1's 12 still in flight
    CONSUME(0);
    SETUP(0, t2); ISSUE(0);
    WAITV(12);            // T1 done; T2 in flight
    CONSUME(1);
    WAITV(0);             // T2 done
    CONSUME(0);

    __syncthreads();

    // ---- Phase B: vertical 7-tap + std + fused smooth-L1; 2 rows/thread
    float acc = 0.0f;
    {
        const int rp = tid >> 4;          // row pair 0..15
        const int x  = (tid & 15) << 2;   // col within tile

        f32x4 pA, pB;                     // input 0 std quads

        #define STD4(Sv, Qv, D) do {                                         \
            _Pragma("unroll")                                                \
            for (int c_ = 0; c_ < 4; ++c_) {                                 \
                float mu_ = (Sv)[c_] * INV_N;                                \
                (D)[c_] = sqrtf(fmaf(-mu_, mu_, (Qv)[c_] * INV_N) + 1e-8f);  \
            }                                                                \
        } while (0)
        #define SL1(a, bb) do {                                              \
            float d_  = (a) - (bb);                                          \
            float ad_ = fabsf(d_);                                           \
            acc += (ad_ < 1.0f) ? 0.5f * d_ * d_ : (ad_ - 0.5f);             \
        } while (0)

        #pragma unroll
        for (int w = 0; w < 2; ++w) {
            f32x4 S = (f32x4){0.f, 0.f, 0.f, 0.f};
            f32x4 Q = (f32x4){0.f, 0.f, 0.f, 0.f};
            #pragma unroll
            for (int k = 0; k < K; ++k) {
                S += *(const f32x4*)&sh_s[w][2 * rp + k][x];
                Q += *(const f32x4*)&sh_q[w][2 * rp + k][x];
            }
            f32x4 S2 = S - *(const f32x4*)&sh_s[w][2 * rp][x]
                         + *(const f32x4*)&sh_s[w][2 * rp + 7][x];
            f32x4 Q2 = Q - *(const f32x4*)&sh_q[w][2 * rp][x]
                         + *(const f32x4*)&sh_q[w][2 * rp + 7][x];

            if (w == 0) {
                STD4(S, Q, pA);
                STD4(S2, Q2, pB);
            } else {
                f32x4 sA, sB;
                STD4(S, Q, sA);
                STD4(S2, Q2, sB);
                SL1(pA[0], sA[0]); SL1(pA[1], sA[1]);
                SL1(pA[2], sA[2]); SL1(pA[3], sA[3]);
                SL1(pB[0], sB[0]); SL1(pB[1], sB[1]);
                SL1(pB[2], sB[2]); SL1(pB[3], sB[3]);
            }
        }
        #undef STD4
        #undef SL1
    }

    // ---- block reduction: wave64 shuffle, cross-wave via LDS, one atomic
    #pragma unroll
    for (int off = 32; off > 0; off >>= 1)
        acc += __shfl_down(acc, off, 64);

    __shared__ float wave_sums[NT / 64];
    if ((tid & 63) == 0) wave_sums[tid >> 6] = acc;
    __syncthreads();
    if (tid == 0) {
        float s = 0.0f;
        #pragma unroll
        for (int w = 0; w < NT / 64; ++w) s += wave_sums[w];
        atomicAdd(out, s * INV_TOTAL);
    }
}

extern "C" void kernel_launch(void* const* d_in, const int* in_sizes, int n_in,
                              void* d_out, int out_size, void* d_ws, size_t ws_size,
                              hipStream_t stream) {
    const float* pred = (const float*)d_in[0];
    const float* tgt  = (const float*)d_in[1];
    float* out = (float*)d_out;

    hipMemsetAsync(out, 0, sizeof(float), stream);

    dim3 grid(512 / TSX, 512 / TSY, 16);   // 8 x 16 x 16 = 2048 blocks
    dist_loss_kernel<<<grid, NT, 0, stream>>>(pred, tgt, out);
}